// Round 5
// baseline (203.196 us; speedup 1.0000x reference)
//
#include <hip/hip_runtime.h>
#include <hip/hip_bf16.h>

// ---------------------------------------------------------------------------
// CVXPolicy_DoubleIntegrator, R5: barrier-free streaming, weights from L1/L2.
//
// Packed weights (bf16, scatter folded into W3, t-row of W1 removed):
//   PW1: frag (kt*7+nt), kt<6, nt<7        -> shorts [0, 21504)
//   PW2: frag 42+kt*7+nt, kt<4, nt<7       -> shorts [21504, 35840)
//   PW3: frag 70+kt*6+nt, kt<4, nt<6       -> shorts [35840, 48128)
//   floats at short-index 48128: w0[112], b1[112], b2[112], bq[96]
// frag = 512 shorts: e = lane*8+j -> B[k = kt*32+(lane>>4)*8+j][n = nt*16+(lane&15)]
//
// MFMA 16x16x32 bf16 layouts (verified R1-R4, passing):
//   A:   lane -> A[m = lane&15][k = (lane>>4)*8 + j]
//   C/D: lane -> col = lane&15, row = (lane>>4)*4 + reg
//
// R2-R4 post-mortem: lockstep [burst load | barrier | LDS compute | store]
// phases serialize; 66-68 us regardless of occupancy. R5: NO barriers, no
// weight staging. Each wave = independent 16-row pipeline; B-frags loaded
// global->reg (94 KB set, L1/L2-hot) interleaved 1:1 with MFMAs; z/out are
// nontemporal to preserve L1 for weights. 2048 blocks x 4 waves de-phase to
// keep VMEM+LDS+VALU+MFMA busy concurrently.
// ---------------------------------------------------------------------------

typedef __attribute__((ext_vector_type(8))) short short8;
typedef __attribute__((ext_vector_type(4))) short short4v;
typedef __attribute__((ext_vector_type(4))) float f32x4;

#define HST 116  // hbuf row stride in shorts (232 B: 8B-aligned)

__device__ __forceinline__ unsigned short f2bf(float f) {
  unsigned u = __float_as_uint(f);
  u += 0x7fffu + ((u >> 16) & 1u);  // RNE (finite values only)
  return (unsigned short)(u >> 16);
}
__device__ __forceinline__ float tanh_fast(float x) {
  float ax = fabsf(x);
  float e = __builtin_amdgcn_exp2f(ax * -2.88539008177792681f);  // exp(-2ax)
  float r = (1.f - e) * __builtin_amdgcn_rcpf(1.f + e);
  return copysignf(r, x);
}

// ---------------------------------------------------------------------------
// Prep: pack weights bf16, fold scatter into W3, drop t-row (kept as w0 f32).
// ---------------------------------------------------------------------------
__global__ void cvx_prep(const float* __restrict__ W1, const float* __restrict__ b1,
                         const float* __restrict__ W2, const float* __restrict__ b2,
                         const float* __restrict__ W3, const float* __restrict__ b3,
                         short* __restrict__ pw) {
  int idx = blockIdx.x * 256 + threadIdx.x;

  if (idx < 21504) {                        // PW1: 6 kt * 7 nt * 512
    int kt = idx / 3584, rem = idx % 3584;
    int nt = rem / 512, e = rem % 512;
    int lane = e >> 3, j = e & 7;
    int k = kt * 32 + (lane >> 4) * 8 + j;  // z index; W1 row k+1
    int n = nt * 16 + (lane & 15);
    float wv = (n < 100) ? W1[(k + 1) * 100 + n] : 0.f;
    pw[(kt * 7 + nt) * 512 + e] = (short)f2bf(wv);
    return;
  }
  idx -= 21504;
  if (idx < 14336) {                        // PW2: 4 kt * 7 nt * 512
    int kt = idx / 3584, rem = idx % 3584;
    int nt = rem / 512, e = rem % 512;
    int lane = e >> 3, j = e & 7;
    int k = kt * 32 + (lane >> 4) * 8 + j;
    int n = nt * 16 + (lane & 15);
    float wv = (k < 100 && n < 100) ? W2[k * 100 + n] : 0.f;
    pw[21504 + (kt * 7 + nt) * 512 + e] = (short)f2bf(wv);
    return;
  }
  idx -= 14336;
  if (idx < 12288) {                        // PW3 folded: 4 kt * 6 nt * 512
    int kt = idx / 3072, rem = idx % 3072;
    int nt = rem / 512, e = rem % 512;
    int lane = e >> 3, j = e & 7;
    int k = kt * 32 + (lane >> 4) * 8 + j;
    int u = nt * 16 + (lane & 15);          // u < 96
    float wv = 0.f;
    if (k < 100) {
      const float* wr = W3 + k * 192;
      if (u <= 31) wv += wr[3 * u + 3];                     // u = i
      if ((u & 1) == 0 && u <= 62) wv += wr[2 * u + 4];     // u = 2i
      if (u % 3 == 0 && u <= 93) wv += wr[(5 * u) / 3 + 5]; // u = 3i
    }
    pw[35840 + (kt * 6 + nt) * 512 + e] = (short)f2bf(wv);
    return;
  }
  idx -= 12288;
  float* cb = (float*)(pw + 48128);
  if (idx < 112) { cb[idx] = (idx < 100) ? W1[idx] : 0.f; return; }        // w0 = W1 row 0
  idx -= 112;
  if (idx < 112) { cb[112 + idx] = (idx < 100) ? b1[idx] : 0.f; return; }
  idx -= 112;
  if (idx < 112) { cb[224 + idx] = (idx < 100) ? b2[idx] : 0.f; return; }
  idx -= 112;
  if (idx < 96) {
    int u = idx;
    float v = 0.f;
    if (u <= 31) v += b3[3 * u + 3];
    if ((u & 1) == 0 && u <= 62) v += b3[2 * u + 4];
    if (u % 3 == 0 && u <= 93) v += b3[(5 * u) / 3 + 5];
    cb[336 + u] = v;
  }
}

// ---------------------------------------------------------------------------
// Main: 256 thr (4 waves) x 2048 blocks; each wave owns 16 rows, no barriers.
// ---------------------------------------------------------------------------
__global__ __launch_bounds__(256) void cvx_main(
    const float* __restrict__ zin, const float* __restrict__ tin,
    const short* __restrict__ pw, float* __restrict__ out) {
  __shared__ __align__(16) short hbuf[4 * 16 * HST];  // 14,848 B, wave-private regions

  const int tid = threadIdx.x;
  const int wid = tid >> 6;
  const int lane = tid & 63;
  const int l15 = lane & 15;
  const int qd = lane >> 4;

  const int rb = blockIdx.x * 64 + wid * 16;   // wave's first row
  const int hb = wid * 16 * HST;
  const float* cb = (const float*)(pw + 48128);  // w0/b1/b2/bq (L1-hot)

  // ---- load z,t (nontemporal: no reuse, keep L1 for weights), cvt to bf16 ----
  short8 XA[6];
  float tcur;
  {
    const float* zr = zin + (size_t)(rb + l15) * 192 + qd * 8;
    f32x4 za[6], zb[6];
#pragma unroll
    for (int kt = 0; kt < 6; kt++) {
      za[kt] = __builtin_nontemporal_load((const f32x4*)(zr + kt * 32));
      zb[kt] = __builtin_nontemporal_load((const f32x4*)(zr + kt * 32 + 4));
    }
    tcur = tin[rb + l15];
#pragma unroll
    for (int kt = 0; kt < 6; kt++) {
      union { short8 s; __hip_bfloat162 h[4]; } u;
      u.h[0] = __float22bfloat162_rn(make_float2(za[kt][0], za[kt][1]));
      u.h[1] = __float22bfloat162_rn(make_float2(za[kt][2], za[kt][3]));
      u.h[2] = __float22bfloat162_rn(make_float2(zb[kt][0], zb[kt][1]));
      u.h[3] = __float22bfloat162_rn(make_float2(zb[kt][2], zb[kt][3]));
      XA[kt] = u.s;
    }
  }

  auto ldw = [&](int f) -> short8 {   // weight B-frag: global (L1/L2-hot)
    return *(const short8*)(pw + f * 512 + lane * 8);
  };
  auto ldh = [&](int off) -> short8 {  // 8B-aligned LDS read of 8 shorts
    short4v a = *(const short4v*)&hbuf[off];
    short4v b = *(const short4v*)&hbuf[off + 4];
    return __builtin_shufflevector(a, b, 0, 1, 2, 3, 4, 5, 6, 7);
  };

  // ---- Layer 1: [16,192] x [192,112] ----
  f32x4 acc[7];
#pragma unroll
  for (int nt = 0; nt < 7; nt++) { f32x4 z4 = {0.f, 0.f, 0.f, 0.f}; acc[nt] = z4; }
#pragma unroll
  for (int kt = 0; kt < 6; kt++)
#pragma unroll
    for (int nt = 0; nt < 7; nt++)
      acc[nt] = __builtin_amdgcn_mfma_f32_16x16x32_bf16(XA[kt], ldw(kt * 7 + nt), acc[nt], 0, 0, 0);
  // t rank-1 fixup + bias + tanh -> hbuf
  float tr[4];
#pragma unroll
  for (int r = 0; r < 4; r++) tr[r] = __shfl(tcur, qd * 4 + r);
#pragma unroll
  for (int nt = 0; nt < 7; nt++) {
    float w0n = cb[nt * 16 + l15];
    float b1n = cb[112 + nt * 16 + l15];
#pragma unroll
    for (int r = 0; r < 4; r++) {
      float v = fmaf(tr[r], w0n, acc[nt][r] + b1n);
      hbuf[hb + (qd * 4 + r) * HST + nt * 16 + l15] = (short)f2bf(tanh_fast(v));
    }
  }

  // ---- Layer 2: [16,128] x [128,112] (K rows 100..127 are B-zero) ----
  short8 HA[4];
  {
    int ro = hb + l15 * HST;
#pragma unroll
    for (int kt = 0; kt < 3; kt++) HA[kt] = ldh(ro + kt * 32 + qd * 8);
    HA[3] = ldh(ro + 96 + (qd & 1) * 8);  // k>=100 lanes: value x B-zero = 0
  }
#pragma unroll
  for (int nt = 0; nt < 7; nt++) { f32x4 z4 = {0.f, 0.f, 0.f, 0.f}; acc[nt] = z4; }
#pragma unroll
  for (int kt = 0; kt < 4; kt++)
#pragma unroll
    for (int nt = 0; nt < 7; nt++)
      acc[nt] = __builtin_amdgcn_mfma_f32_16x16x32_bf16(HA[kt], ldw(42 + kt * 7 + nt), acc[nt], 0, 0, 0);
#pragma unroll
  for (int nt = 0; nt < 7; nt++) {
    float b2n = cb[224 + nt * 16 + l15];
#pragma unroll
    for (int r = 0; r < 4; r++)
      hbuf[hb + (qd * 4 + r) * HST + nt * 16 + l15] = (short)f2bf(tanh_fast(acc[nt][r] + b2n));
  }

  // ---- Layer 3 (scatter-folded): [16,128] x [128,96] -> q ----
  {
    int ro = hb + l15 * HST;
#pragma unroll
    for (int kt = 0; kt < 3; kt++) HA[kt] = ldh(ro + kt * 32 + qd * 8);
    HA[3] = ldh(ro + 96 + (qd & 1) * 8);
  }
  f32x4 qa[6];
#pragma unroll
  for (int nt = 0; nt < 6; nt++) { f32x4 z4 = {0.f, 0.f, 0.f, 0.f}; qa[nt] = z4; }
#pragma unroll
  for (int kt = 0; kt < 4; kt++)
#pragma unroll
    for (int nt = 0; nt < 6; nt++)
      qa[nt] = __builtin_amdgcn_mfma_f32_16x16x32_bf16(HA[kt], ldw(70 + kt * 6 + nt), qa[nt], 0, 0, 0);

  // ---- QP epilogue: r2 = ||q||^2, Newton s(1+s)^2 = r2, u = -q/(1+s) ----
#pragma unroll
  for (int nt = 0; nt < 6; nt++) {
    float bq = cb[336 + nt * 16 + l15];
    qa[nt][0] += bq; qa[nt][1] += bq; qa[nt][2] += bq; qa[nt][3] += bq;
  }
  f32x4 rs = {0.f, 0.f, 0.f, 0.f};
#pragma unroll
  for (int nt = 0; nt < 6; nt++) rs += qa[nt] * qa[nt];
  float rv[4];
#pragma unroll
  for (int r = 0; r < 4; r++) {
    float v = rs[r];
    v += __shfl_xor(v, 1);
    v += __shfl_xor(v, 2);
    v += __shfl_xor(v, 4);
    v += __shfl_xor(v, 8);
    rv[r] = v;
  }
  float r2 = rv[l15 & 3];
  float s = __builtin_amdgcn_exp2f(__builtin_amdgcn_logf(r2) * 0.333333333333f);
#pragma unroll
  for (int itn = 0; itn < 8; itn++) {
    float one = 1.f + s;
    float fv = fmaf(s * one, one, -r2);
    float fp = one * fmaf(2.f, s, one);
    s = fmaxf(s - fv * __builtin_amdgcn_rcpf(fp), 0.f);
  }
  float myinv = -__builtin_amdgcn_rcpf(1.f + s);
#pragma unroll
  for (int r = 0; r < 4; r++) {
    float inv = __shfl(myinv, (lane & 48) | r);
    float* orow = out + (size_t)(rb + qd * 4 + r) * 96;
#pragma unroll
    for (int nt = 0; nt < 6; nt++)
      __builtin_nontemporal_store(qa[nt][r] * inv, &orow[nt * 16 + l15]);
  }
}

extern "C" void kernel_launch(void* const* d_in, const int* in_sizes, int n_in,
                              void* d_out, int out_size, void* d_ws, size_t ws_size,
                              hipStream_t stream) {
  const float* z  = (const float*)d_in[0];
  const float* t  = (const float*)d_in[1];
  const float* W1 = (const float*)d_in[2];
  const float* b1 = (const float*)d_in[3];
  const float* W2 = (const float*)d_in[4];
  const float* b2 = (const float*)d_in[5];
  const float* W3 = (const float*)d_in[6];
  const float* b3 = (const float*)d_in[7];
  float* out = (float*)d_out;
  int B = in_sizes[0] / 192;                 // 131072

  short* pw = (short*)d_ws;                  // 97,984 bytes used
  cvx_prep<<<190, 256, 0, stream>>>(W1, b1, W2, b2, W3, b3, pw);
  cvx_main<<<B / 64, 256, 0, stream>>>(z, t, pw, out);
}